// Round 5
// baseline (1094.458 us; speedup 1.0000x reference)
//
#include <hip/hip_runtime.h>
#include <math.h>

// ---------------------------------------------------------------------------
// CogKR pipeline, R5.
// R4 failed POST-TIMING only (first launch correct, replays diverged 0.18):
// a scheduling-sensitive race in the new double-buffered gemm16bf_k /
// score_mfma2_k is the prime suspect. R5 reverts to single-LDS-buffer,
// two-barrier structures (R3-proven class) while keeping R4's wins:
//  - gemm16s_k: BK=64, register prefetch of NEXT tile issued after the
//    visibility barrier (overlaps compute), XOR-swizzled LDS, bf16 epilogue
//    restaged through LDS for coalesced 16B/lane stores.
//  - score_mfma3_k: R3's proven score kernel, A staged from entity16 (bf16),
//    hnewCand read as bf16.
//  - bf16 intermediates everywhere (entity16/agg/h_prev/h_new/hnewCand/gx/gh).
// ws ~236 MB.
// ---------------------------------------------------------------------------

#define ACT_NONE 0
#define ACT_LRELU 1

typedef __attribute__((ext_vector_type(8))) short short8;
typedef __attribute__((ext_vector_type(4))) float floatx4;

__device__ __forceinline__ ushort f2b(float x) {
    union { float f; unsigned u; } v; v.f = x;
    return (ushort)((v.u + 0x7fffu + ((v.u >> 16) & 1u)) >> 16);
}
__device__ __forceinline__ float b2f(ushort b) {
    union { unsigned u; float f; } v; v.u = ((unsigned)b) << 16;
    return v.f;
}

// ---------------- small fp32 tiled GEMM (relation tables only) ----------------
__global__ __launch_bounds__(256) void gemm_k(
    const float* __restrict__ A, const float* __restrict__ B,
    const float* __restrict__ bias, float* __restrict__ C,
    int M, int N, int K, const int* __restrict__ a_idx, int act)
{
    __shared__ float As[16][68];
    __shared__ float Bs[16][68];
    const int tid = threadIdx.x;
    const int tx = tid & 15, ty = tid >> 4;
    const int m0 = blockIdx.x * 64, n0 = blockIdx.y * 64;
    float acc[4][4] = {};
    const int ar  = tid >> 2;
    const int ac4 = (tid & 3) * 4;
    const int brow = tid >> 4;
    const int bc4  = (tid & 15) * 4;
    const int gm = m0 + ar;
    const float* Arow = nullptr;
    if (gm < M) {
        int r = a_idx ? a_idx[gm] : gm;
        Arow = A + (size_t)r * K;
    }
    for (int k0 = 0; k0 < K; k0 += 16) {
        float4 av = make_float4(0.f, 0.f, 0.f, 0.f);
        if (Arow) av = *(const float4*)(Arow + k0 + ac4);
        As[ac4 + 0][ar] = av.x;
        As[ac4 + 1][ar] = av.y;
        As[ac4 + 2][ar] = av.z;
        As[ac4 + 3][ar] = av.w;
        float4 bv = *(const float4*)(B + (size_t)(k0 + brow) * N + n0 + bc4);
        *(float4*)&Bs[brow][bc4] = bv;
        __syncthreads();
        #pragma unroll
        for (int kk = 0; kk < 16; ++kk) {
            float4 a4 = *(float4*)&As[kk][ty << 2];
            float4 b4 = *(float4*)&Bs[kk][tx << 2];
            float avr[4] = {a4.x, a4.y, a4.z, a4.w};
            float bvr[4] = {b4.x, b4.y, b4.z, b4.w};
            #pragma unroll
            for (int i = 0; i < 4; ++i)
                #pragma unroll
                for (int j = 0; j < 4; ++j)
                    acc[i][j] = fmaf(avr[i], bvr[j], acc[i][j]);
        }
        __syncthreads();
    }
    const int n = n0 + (tx << 2);
    float4 bv4 = make_float4(0.f, 0.f, 0.f, 0.f);
    if (bias) bv4 = *(const float4*)(bias + n);
    #pragma unroll
    for (int i = 0; i < 4; ++i) {
        int m = m0 + (ty << 2) + i;
        if (m >= M) continue;
        float v0 = acc[i][0] + bv4.x;
        float v1 = acc[i][1] + bv4.y;
        float v2 = acc[i][2] + bv4.z;
        float v3 = acc[i][3] + bv4.w;
        if (act == ACT_LRELU) {
            v0 = v0 > 0.f ? v0 : 0.01f * v0;
            v1 = v1 > 0.f ? v1 : 0.01f * v1;
            v2 = v2 > 0.f ? v2 : 0.01f * v2;
            v3 = v3 > 0.f ? v3 : 0.01f * v3;
        }
        *(float4*)(C + (size_t)m * N + n) = make_float4(v0, v1, v2, v3);
    }
}

// ---------------- fp32 -> bf16, vectorized x4 ----------------
__global__ __launch_bounds__(256) void conv4_k(
    const float* __restrict__ in, ushort* __restrict__ out, int n4)
{
    int i = blockIdx.x * 256 + threadIdx.x;
    if (i >= n4) return;
    float4 v = *(const float4*)(in + (size_t)i * 4);
    ushort4 o;
    o.x = f2b(v.x); o.y = f2b(v.y); o.z = f2b(v.z); o.w = f2b(v.w);
    *(ushort4*)(out + (size_t)i * 4) = o;
}

// ---------------- out[N][KS] = bf16(in[k0+k][n]), in row-major [*, N] ----------------
__global__ __launch_bounds__(256) void transpose16_k(
    const float* __restrict__ in, ushort* __restrict__ out, int k0, int KS, int N)
{
    int i = blockIdx.x * 256 + threadIdx.x;
    if (i >= KS * N) return;
    int k = i / N, n = i - k * N;
    out[(size_t)n * KS + k] = f2b(in[(size_t)(k0 + k) * N + n]);
}

// ---------------- bf16 MFMA GEMM, single-buffer, reg-prefetch ----------------
// C16 = bf16(act(A@B + bias)). A fp32 (Af) or bf16 (A16), optional row gather.
// BT bf16 [N,K]. K%64==0, N%128==0. 128x128 tile, BK=64, 256 threads.
// Loop: stage LDS -> barrier -> issue next-tile global loads -> MFMA -> barrier.
__global__ __launch_bounds__(256) void gemm16s_k(
    const float* __restrict__ Af, const ushort* __restrict__ A16,
    const int* __restrict__ a_idx, const ushort* __restrict__ BT,
    const float* __restrict__ bias, ushort* __restrict__ C16,
    int M, int N, int K, int act)
{
    __shared__ ushort lds[16384];   // A: [0,8192), B: [8192,16384); epilogue: C tile
    const int tid = threadIdx.x;
    const int m0 = blockIdx.x * 128, n0 = blockIdx.y * 128;
    const int nk = K >> 6;

    // staging maps: 4 slots/thread, slot -> (row 0..127, 16B seg 0..7), XOR swizzle
    int sofs[4];
    const float* aptrF[4];
    const ushort* aptrH[4];
    const ushort* bptr[4];
    bool avalid[4];
    #pragma unroll
    for (int i = 0; i < 4; ++i) {
        int slot = tid + i * 256;
        int row = slot >> 3, seg = slot & 7;
        sofs[i] = row * 64 + ((seg ^ (row & 7)) << 3);
        int gr = m0 + row;
        avalid[i] = (gr < M);
        int ridx = avalid[i] ? (a_idx ? a_idx[gr] : gr) : 0;
        aptrF[i] = Af  ? Af  + (size_t)ridx * K + seg * 8 : nullptr;
        aptrH[i] = A16 ? A16 + (size_t)ridx * K + seg * 8 : nullptr;
        bptr[i]  = BT + (size_t)(n0 + row) * K + seg * 8;
    }

    float4 pf0[4], pf1[4]; uint4 pfh[4]; uint4 pfb[4];
    auto ld = [&](int k0) {
        #pragma unroll
        for (int i = 0; i < 4; ++i) {
            if (Af) {
                if (avalid[i]) {
                    pf0[i] = *(const float4*)(aptrF[i] + k0);
                    pf1[i] = *(const float4*)(aptrF[i] + k0 + 4);
                }
            } else {
                if (avalid[i]) pfh[i] = *(const uint4*)(aptrH[i] + k0);
            }
            pfb[i] = *(const uint4*)(bptr[i] + k0);
        }
    };
    auto st = [&]() {
        #pragma unroll
        for (int i = 0; i < 4; ++i) {
            if (Af) {
                short8 v;
                if (avalid[i]) {
                    v[0] = (short)f2b(pf0[i].x); v[1] = (short)f2b(pf0[i].y);
                    v[2] = (short)f2b(pf0[i].z); v[3] = (short)f2b(pf0[i].w);
                    v[4] = (short)f2b(pf1[i].x); v[5] = (short)f2b(pf1[i].y);
                    v[6] = (short)f2b(pf1[i].z); v[7] = (short)f2b(pf1[i].w);
                } else {
                    #pragma unroll
                    for (int j = 0; j < 8; ++j) v[j] = 0;
                }
                *(short8*)&lds[sofs[i]] = v;
            } else {
                uint4 u = avalid[i] ? pfh[i] : make_uint4(0u, 0u, 0u, 0u);
                *(uint4*)&lds[sofs[i]] = u;
            }
            *(uint4*)&lds[8192 + sofs[i]] = pfb[i];
        }
    };

    const int l = tid & 63, w = tid >> 6;
    const int wm = (w & 1) * 64, wn = (w >> 1) * 64;
    const int cl = l & 15, q = l >> 4;
    int aofs[4][2], bofs[4][2];
    #pragma unroll
    for (int mi = 0; mi < 4; ++mi) {
        int rA = wm + mi * 16 + cl;
        int rB = wn + mi * 16 + cl;
        #pragma unroll
        for (int kk = 0; kk < 2; ++kk) {
            int s = kk * 4 + q;
            aofs[mi][kk] = rA * 64 + ((s ^ (rA & 7)) << 3);
            bofs[mi][kk] = 8192 + rB * 64 + ((s ^ (rB & 7)) << 3);
        }
    }

    floatx4 acc[4][4];
    #pragma unroll
    for (int mi = 0; mi < 4; ++mi)
        #pragma unroll
        for (int ni = 0; ni < 4; ++ni) acc[mi][ni] = 0.f;

    ld(0);
    for (int kt = 0; kt < nk; ++kt) {
        st();
        __syncthreads();
        if (kt + 1 < nk) ld((kt + 1) << 6);   // overlaps with MFMA below
        #pragma unroll
        for (int kk = 0; kk < 2; ++kk) {
            short8 af[4], bf[4];
            #pragma unroll
            for (int mi = 0; mi < 4; ++mi) af[mi] = *(short8*)&lds[aofs[mi][kk]];
            #pragma unroll
            for (int ni = 0; ni < 4; ++ni) bf[ni] = *(short8*)&lds[bofs[ni][kk]];
            #pragma unroll
            for (int mi = 0; mi < 4; ++mi)
                #pragma unroll
                for (int ni = 0; ni < 4; ++ni)
                    acc[mi][ni] = __builtin_amdgcn_mfma_f32_16x16x32_bf16(
                        af[mi], bf[ni], acc[mi][ni], 0, 0, 0);
        }
        __syncthreads();   // protect LDS before next iteration's st()
    }

    // epilogue: restage bf16 C tile (full lds = 128x128 ushorts), coalesced stores
    #pragma unroll
    for (int ni = 0; ni < 4; ++ni) {
        int col = wn + ni * 16 + cl;
        float bv = bias ? bias[n0 + col] : 0.f;
        #pragma unroll
        for (int mi = 0; mi < 4; ++mi) {
            int row0 = wm + mi * 16 + q * 4;
            #pragma unroll
            for (int r = 0; r < 4; ++r) {
                float v = acc[mi][ni][r] + bv;
                if (act == ACT_LRELU) v = v > 0.f ? v : 0.01f * v;
                lds[(row0 + r) * 128 + col] = f2b(v);
            }
        }
    }
    __syncthreads();
    #pragma unroll
    for (int i = 0; i < 8; ++i) {
        int slot = tid + i * 256;
        int row = slot >> 4, seg = slot & 15;
        int gr = m0 + row;
        if (gr < M)
            *(uint4*)(C16 + (size_t)gr * N + n0 + seg * 8) = *(uint4*)&lds[row * 128 + seg * 8];
    }
}

// ---------------- qdot[b] = query_repr[b] . rank_W[256:512] ----------------
__global__ __launch_bounds__(256) void qdot_k(
    const float* __restrict__ q, const float* __restrict__ rank_W,
    float* __restrict__ qdot)
{
    int b = blockIdx.x * 4 + (threadIdx.x >> 6);
    int l = threadIdx.x & 63;
    float s = 0.f;
    #pragma unroll
    for (int k = 0; k < 4; ++k) {
        int h = l + k * 64;
        s += q[(size_t)b * 256 + h] * rank_W[256 + h];
    }
    #pragma unroll
    for (int off = 32; off; off >>= 1) s += __shfl_xor(s, off, 64);
    if (l == 0) qdot[b] = s;
}

// ---------------- per-edge attention alpha (nodeWs in bf16) ----------------
__global__ __launch_bounds__(256) void alpha_k(
    const ushort* __restrict__ nodeWs16, const float* __restrict__ relWr,
    const float* __restrict__ relWqr, const float* __restrict__ bqr,
    const float* __restrict__ w_alpha, const float* __restrict__ b_alpha_p,
    const int* __restrict__ head_node, const int* __restrict__ edge_rel,
    const int* __restrict__ query_rel, float* __restrict__ alpha_out)
{
    const int tid = threadIdx.x;
    const int e0 = blockIdx.x * 32;
    __shared__ int hn[32], er[32], qr[32];
    if (tid < 32) {
        int e = e0 + tid;
        hn[tid] = head_node[e]; er[tid] = edge_rel[e]; qr[tid] = query_rel[e];
    }
    __syncthreads();
    const int tx = tid & 63, ty = tid >> 6;
    const int c = tx * 4;
    const float4 bq = *(const float4*)(bqr + c);
    const float4 wa = *(const float4*)(w_alpha + c);
    float part[8];
    #pragma unroll
    for (int i2 = 0; i2 < 8; ++i2) {
        int i = ty * 8 + i2;
        ushort4 a16 = *(const ushort4*)(nodeWs16 + (size_t)hn[i] * 256 + c);
        float4 b = *(const float4*)(relWr + (size_t)er[i] * 256 + c);
        float4 d = *(const float4*)(relWqr + (size_t)qr[i] * 256 + c);
        float x0 = fmaxf(b2f(a16.x) + b.x + d.x + bq.x, 0.f);
        float x1 = fmaxf(b2f(a16.y) + b.y + d.y + bq.y, 0.f);
        float x2 = fmaxf(b2f(a16.z) + b.z + d.z + bq.z, 0.f);
        float x3 = fmaxf(b2f(a16.w) + b.w + d.w + bq.w, 0.f);
        part[i2] = x0 * wa.x + x1 * wa.y + x2 * wa.z + x3 * wa.w;
    }
    #pragma unroll
    for (int off = 32; off; off >>= 1)
        #pragma unroll
        for (int i2 = 0; i2 < 8; ++i2)
            part[i2] += __shfl_xor(part[i2], off, 64);
    if (tx == 0) {
        float ba = b_alpha_p[0];
        #pragma unroll
        for (int i2 = 0; i2 < 8; ++i2)
            alpha_out[e0 + ty * 8 + i2] = 1.f / (1.f + __expf(-(part[i2] + ba)));
    }
}

// ---------------- CSR build ----------------
__global__ __launch_bounds__(256) void hist_k(
    const int* __restrict__ tail_node, int* __restrict__ deg, int M)
{
    int e = blockIdx.x * 256 + threadIdx.x;
    if (e < M) atomicAdd(&deg[tail_node[e]], 1);
}
__global__ __launch_bounds__(256) void scan1_k(
    const int* __restrict__ deg, int* __restrict__ partial, int N)
{
    __shared__ int sm[256];
    int i = blockIdx.x * 256 + threadIdx.x;
    int v = (i < N) ? deg[i] : 0;
    sm[threadIdx.x] = v;
    __syncthreads();
    for (int off = 128; off; off >>= 1) {
        if (threadIdx.x < off) sm[threadIdx.x] += sm[threadIdx.x + off];
        __syncthreads();
    }
    if (threadIdx.x == 0) partial[blockIdx.x] = sm[0];
}
__global__ __launch_bounds__(256) void scan2_k(
    int* __restrict__ partial, int nPart, int* __restrict__ offsets, int N, int M)
{
    __shared__ int sm[256];
    int t = threadIdx.x;
    int v = (t < nPart) ? partial[t] : 0;
    sm[t] = v;
    __syncthreads();
    for (int off = 1; off < 256; off <<= 1) {
        int add = (t >= off) ? sm[t - off] : 0;
        __syncthreads();
        sm[t] += add;
        __syncthreads();
    }
    if (t < nPart) partial[t] = sm[t] - v;
    if (t == 0) offsets[N] = M;
}
__global__ __launch_bounds__(256) void scan3_k(
    const int* __restrict__ deg, const int* __restrict__ partial,
    int* __restrict__ offsets, int* __restrict__ cursor, int N)
{
    __shared__ int sm[256];
    int i = blockIdx.x * 256 + threadIdx.x;
    int t = threadIdx.x;
    int v = (i < N) ? deg[i] : 0;
    sm[t] = v;
    __syncthreads();
    for (int off = 1; off < 256; off <<= 1) {
        int add = (t >= off) ? sm[t - off] : 0;
        __syncthreads();
        sm[t] += add;
        __syncthreads();
    }
    if (i < N) {
        int excl = partial[blockIdx.x] + sm[t] - v;
        offsets[i] = excl;
        cursor[i] = excl;
    }
}
__global__ __launch_bounds__(256) void fill_k(
    const int* __restrict__ tail_node, int* __restrict__ cursor,
    int* __restrict__ csr, int M)
{
    int e = blockIdx.x * 256 + threadIdx.x;
    if (e < M) {
        int pos = atomicAdd(&cursor[tail_node[e]], 1);
        csr[pos] = e;
    }
}

// ---------------- segment-sum via CSR gather-reduce -> bf16 agg ----------------
__global__ __launch_bounds__(256) void agg_csr16_k(
    const float* __restrict__ relation_emb, const ushort* __restrict__ ent16,
    const float* __restrict__ alpha, const int* __restrict__ edge_rel,
    const int* __restrict__ tail_ent, const int* __restrict__ offsets,
    const int* __restrict__ csr, ushort* __restrict__ agg16)
{
    int node = blockIdx.x * 4 + (threadIdx.x >> 6);
    int lane = threadIdx.x & 63;
    int beg = offsets[node], end = offsets[node + 1];
    int c = lane * 4;
    float4 acc = make_float4(0.f, 0.f, 0.f, 0.f);
    if (c < 128) {
        for (int j = beg; j < end; ++j) {
            int e = csr[j];
            float a = alpha[e];
            float4 v = *(const float4*)(relation_emb + (size_t)edge_rel[e] * 128 + c);
            acc.x += v.x * a; acc.y += v.y * a; acc.z += v.z * a; acc.w += v.w * a;
        }
    } else {
        for (int j = beg; j < end; ++j) {
            int e = csr[j];
            float a = alpha[e];
            ushort4 u = *(const ushort4*)(ent16 + (size_t)tail_ent[e] * 128 + (c - 128));
            acc.x += b2f(u.x) * a; acc.y += b2f(u.y) * a;
            acc.z += b2f(u.z) * a; acc.w += b2f(u.w) * a;
        }
    }
    ushort4 o;
    o.x = f2b(acc.x); o.y = f2b(acc.y); o.z = f2b(acc.z); o.w = f2b(acc.w);
    *(ushort4*)(agg16 + (size_t)node * 256 + c) = o;
}

// ---------------- GRU elementwise + LayerNorm (bf16 in/out) ----------------
__global__ __launch_bounds__(256) void gru_ln16_k(
    const ushort* __restrict__ gx, const ushort* __restrict__ gh,
    const ushort* __restrict__ hp, const float* __restrict__ ln_g,
    const float* __restrict__ ln_b, ushort* __restrict__ h_new, int n0)
{
    int nl = blockIdx.x * 4 + (threadIdx.x >> 6);
    int lane = threadIdx.x & 63;
    int n = n0 + nl;
    const ushort* gxr = gx + (size_t)nl * 768;
    const ushort* ghr = gh + (size_t)nl * 768;
    const ushort* hpr = hp + (size_t)n * 256;
    int c = lane * 4;
    ushort4 xr4 = *(const ushort4*)(gxr + c);
    ushort4 xz4 = *(const ushort4*)(gxr + 256 + c);
    ushort4 xn4 = *(const ushort4*)(gxr + 512 + c);
    ushort4 hr4 = *(const ushort4*)(ghr + c);
    ushort4 hz4 = *(const ushort4*)(ghr + 256 + c);
    ushort4 hn4 = *(const ushort4*)(ghr + 512 + c);
    ushort4 hp4 = *(const ushort4*)(hpr + c);
    float hv[4]; float s = 0.f, s2 = 0.f;
    #pragma unroll
    for (int j = 0; j < 4; ++j) {
        float xr = b2f(((const ushort*)&xr4)[j]);
        float xz = b2f(((const ushort*)&xz4)[j]);
        float xn = b2f(((const ushort*)&xn4)[j]);
        float hr_ = b2f(((const ushort*)&hr4)[j]);
        float hz_ = b2f(((const ushort*)&hz4)[j]);
        float hn_ = b2f(((const ushort*)&hn4)[j]);
        float hpv = b2f(((const ushort*)&hp4)[j]);
        float r = 1.f / (1.f + __expf(-(xr + hr_)));
        float z = 1.f / (1.f + __expf(-(xz + hz_)));
        float nn = tanhf(xn + r * hn_);
        float v = (1.f - z) * nn + z * hpv;
        hv[j] = v; s += v; s2 += v * v;
    }
    #pragma unroll
    for (int off = 32; off; off >>= 1) {
        s  += __shfl_xor(s, off, 64);
        s2 += __shfl_xor(s2, off, 64);
    }
    float mean = s * (1.f / 256.f);
    float var  = s2 * (1.f / 256.f) - mean * mean;
    float rstd = rsqrtf(var + 1e-5f);
    float4 g4 = *(const float4*)(ln_g + c);
    float4 b4 = *(const float4*)(ln_b + c);
    ushort4 o;
    o.x = f2b((hv[0] - mean) * rstd * g4.x + b4.x);
    o.y = f2b((hv[1] - mean) * rstd * g4.y + b4.y);
    o.z = f2b((hv[2] - mean) * rstd * g4.z + b4.z);
    o.w = f2b((hv[3] - mean) * rstd * g4.w + b4.w);
    *(ushort4*)(h_new + (size_t)n * 256 + c) = o;
}

// ---------------- fused score (R3-proven structure, bf16 inputs) ----------------
// 64 edges/block, natural edge order. Wave w owns cols w*64..w*64+63.
__global__ __launch_bounds__(256) void score_mfma3_k(
    const ushort* __restrict__ ent16, const ushort* __restrict__ candW1T,
    const float* __restrict__ relCand, const ushort* __restrict__ hnewCand16,
    const float* __restrict__ rank_W, const float* __restrict__ rank_b_p,
    const float* __restrict__ qdot, const int* __restrict__ tail_ent,
    const int* __restrict__ edge_rel, const int* __restrict__ tail_node,
    const int* __restrict__ batch_idx, float* __restrict__ scores)
{
    __shared__ ushort As[64 * 40];
    __shared__ ushort Bs[256 * 40];
    __shared__ int s_te[64], s_er[64], s_tn[64], s_bi[64];
    __shared__ float s_part[4][64];
    const int tid = threadIdx.x;
    const int e0 = blockIdx.x * 64;
    if (tid < 64) {
        int e = e0 + tid;
        s_te[tid] = tail_ent[e]; s_er[tid] = edge_rel[e];
        s_tn[tid] = tail_node[e]; s_bi[tid] = batch_idx[e];
    }
    __syncthreads();

    const int rowbase = tid >> 3, f4 = tid & 7;           // A: rows rowbase, rowbase+32
    const ushort* ar0 = ent16 + (size_t)s_te[rowbase] * 128;
    const ushort* ar1 = ent16 + (size_t)s_te[rowbase + 32] * 128;
    const int brow = tid >> 2, bseg = tid & 3;            // B: rows brow+i*64, i<4

    const int l = tid & 63, w = tid >> 6;
    const int cl = l & 15, q = l >> 4;
    const int aoff = cl * 40 + q * 8;
    const int boff = (w * 64 + cl) * 40 + q * 8;

    floatx4 acc[4][4];
    #pragma unroll
    for (int mi = 0; mi < 4; ++mi)
        #pragma unroll
        for (int ni = 0; ni < 4; ++ni) acc[mi][ni] = 0.f;

    for (int k0 = 0; k0 < 128; k0 += 32) {
        {
            ushort4 b0 = *(const ushort4*)(ar0 + k0 + f4 * 4);
            ushort4 b1 = *(const ushort4*)(ar1 + k0 + f4 * 4);
            *(ushort4*)&As[rowbase * 40 + f4 * 4] = b0;
            *(ushort4*)&As[(rowbase + 32) * 40 + f4 * 4] = b1;
        }
        #pragma unroll
        for (int i = 0; i < 4; ++i) {
            int r = brow + i * 64;
            uint4 raw = *(const uint4*)(candW1T + (size_t)r * 128 + k0 + bseg * 8);
            *(uint4*)&Bs[r * 40 + bseg * 8] = raw;
        }
        __syncthreads();
        short8 af[4], bf[4];
        #pragma unroll
        for (int mi = 0; mi < 4; ++mi) af[mi] = *(short8*)&As[aoff + mi * 640];
        #pragma unroll
        for (int ni = 0; ni < 4; ++ni) bf[ni] = *(short8*)&Bs[boff + ni * 640];
        #pragma unroll
        for (int mi = 0; mi < 4; ++mi)
            #pragma unroll
            for (int ni = 0; ni < 4; ++ni)
                acc[mi][ni] = __builtin_amdgcn_mfma_f32_16x16x32_bf16(
                    af[mi], bf[ni], acc[mi][ni], 0, 0, 0);
        __syncthreads();
    }

    // epilogue: add relCand[er] + hnewCand[tn], lrelu, dot rank_W, reduce
    float rowsum[4][4];
    #pragma unroll
    for (int mi = 0; mi < 4; ++mi)
        #pragma unroll
        for (int r = 0; r < 4; ++r) rowsum[mi][r] = 0.f;

    #pragma unroll
    for (int ni = 0; ni < 4; ++ni) {
        int col = w * 64 + ni * 16 + cl;
        float rw = rank_W[col];
        #pragma unroll
        for (int mi = 0; mi < 4; ++mi) {
            #pragma unroll
            for (int r = 0; r < 4; ++r) {
                int row = mi * 16 + q * 4 + r;
                float v = acc[mi][ni][r]
                        + relCand[(size_t)s_er[row] * 256 + col]
                        + b2f(hnewCand16[(size_t)s_tn[row] * 256 + col]);
                v = v > 0.f ? v : 0.01f * v;
                rowsum[mi][r] += v * rw;
            }
        }
    }
    #pragma unroll
    for (int mask = 1; mask <= 8; mask <<= 1)
        #pragma unroll
        for (int mi = 0; mi < 4; ++mi)
            #pragma unroll
            for (int r = 0; r < 4; ++r)
                rowsum[mi][r] += __shfl_xor(rowsum[mi][r], mask, 64);
    if (cl == 0) {
        #pragma unroll
        for (int mi = 0; mi < 4; ++mi)
            #pragma unroll
            for (int r = 0; r < 4; ++r)
                s_part[w][mi * 16 + q * 4 + r] = rowsum[mi][r];
    }
    __syncthreads();
    if (tid < 64) {
        float s = s_part[0][tid] + s_part[1][tid] + s_part[2][tid] + s_part[3][tid]
                + qdot[s_bi[tid]] + rank_b_p[0];
        scores[e0 + tid] = s;
    }
}

// ---------------------------------------------------------------------------
extern "C" void kernel_launch(void* const* d_in, const int* in_sizes, int n_in,
                              void* d_out, int out_size, void* d_ws, size_t ws_size,
                              hipStream_t stream)
{
    const float* entity_emb   = (const float*)d_in[0];
    const float* relation_emb = (const float*)d_in[1];
    const float* node_hidden  = (const float*)d_in[2];
    const float* query_repr   = (const float*)d_in[3];
    const float* Ws    = (const float*)d_in[4];
    const float* Wr    = (const float*)d_in[5];
    const float* Wqr   = (const float*)d_in[6];
    const float* bqr   = (const float*)d_in[7];
    const float* w_alpha = (const float*)d_in[8];
    const float* b_alpha = (const float*)d_in[9];
    const float* W_ih  = (const float*)d_in[10];
    const float* W_hh  = (const float*)d_in[11];
    const float* b_ih  = (const float*)d_in[12];
    const float* b_hh  = (const float*)d_in[13];
    const float* We2h_W = (const float*)d_in[14];
    const float* We2h_b = (const float*)d_in[15];
    const float* cand_W = (const float*)d_in[16];
    const float* cand_b = (const float*)d_in[17];
    const float* rank_W = (const float*)d_in[18];
    const float* rank_b = (const float*)d_in[19];
    const float* ln_g  = (const float*)d_in[20];
    const float* ln_b  = (const float*)d_in[21];
    const int* head_node = (const int*)d_in[22];
    const int* edge_rel  = (const int*)d_in[23];
    const int* tail_ent  = (const int*)d_in[24];
    const int* tail_node = (const int*)d_in[25];
    const int* query_rel = (const int*)d_in[26];
    const int* batch_idx = (const int*)d_in[27];
    const int* tail_node_ent = (const int*)d_in[28];
    float* out = (float*)d_out;
    (void)in_sizes; (void)n_in; (void)out_size; (void)ws_size;

    const int M = 200000, NNEW = 50000, NNODES = 100000, NREL = 500;
    const int NCHUNK = 2, NC = NNEW / NCHUNK;   // 25000
    const int NPART = (NNEW + 255) / 256;

    // ---- workspace layout (byte cursor, 256B aligned chunks) ----
    char* base = (char*)d_ws;
    size_t off = 0;
    auto alloc = [&](size_t bytes) -> char* {
        char* p = base + off;
        off += (bytes + 255) & ~(size_t)255;
        return p;
    };
    float* relWr    = (float*)alloc(NREL * 256 * 4);
    float* relWqr   = (float*)alloc(NREL * 256 * 4);
    float* relCand  = (float*)alloc(NREL * 256 * 4);
    float* qdot     = (float*)alloc(256 * 4);
    float* alpha    = (float*)alloc((size_t)M * 4);
    ushort* entity16   = (ushort*)alloc((size_t)200000 * 128 * 2);
    ushort* agg16      = (ushort*)alloc((size_t)NNEW * 256 * 2);
    ushort* h_prev16   = (ushort*)alloc((size_t)NNEW * 256 * 2);
    ushort* h_new16    = (ushort*)alloc((size_t)NNEW * 256 * 2);
    ushort* hnewCand16 = (ushort*)alloc((size_t)NNEW * 256 * 2);
    ushort* W_ih16    = (ushort*)alloc(768 * 256 * 2);
    ushort* W_hh16    = (ushort*)alloc(768 * 256 * 2);
    ushort* WsT16     = (ushort*)alloc(256 * 256 * 2);
    ushort* We2hT16   = (ushort*)alloc(256 * 128 * 2);
    ushort* candW1T16 = (ushort*)alloc(256 * 128 * 2);
    ushort* candW3T16 = (ushort*)alloc(256 * 256 * 2);
    int* deg     = (int*)alloc(NNEW * 4);
    int* offsets = (int*)alloc((NNEW + 1) * 4);
    int* cursor  = (int*)alloc(NNEW * 4);
    int* partial = (int*)alloc(256 * 4);
    int* csr     = (int*)alloc((size_t)M * 4);
    // big region: nodeWs16 (51.2MB, phases 2-3) then gx16|gh16 (76.8MB, phase 6-7)
    char* big = alloc((size_t)NC * 768 * 2 * 2);
    ushort* nodeWs16 = (ushort*)big;
    ushort* gx16 = (ushort*)big;
    ushort* gh16 = (ushort*)(big + (size_t)NC * 768 * 2);

    // (0) CSR build
    hipMemsetAsync(deg, 0, NNEW * sizeof(int), stream);
    hist_k<<<(M + 255) / 256, 256, 0, stream>>>(tail_node, deg, M);
    scan1_k<<<NPART, 256, 0, stream>>>(deg, partial, NNEW);
    scan2_k<<<1, 256, 0, stream>>>(partial, NPART, offsets, NNEW, M);
    scan3_k<<<NPART, 256, 0, stream>>>(deg, partial, offsets, cursor, NNEW);
    fill_k<<<(M + 255) / 256, 256, 0, stream>>>(tail_node, cursor, csr, M);

    // (1) conversions + relation tables + qdot
    conv4_k<<<25000, 256, 0, stream>>>(entity_emb, entity16, 200000 * 128 / 4);
    conv4_k<<<192, 256, 0, stream>>>(W_ih, W_ih16, 768 * 256 / 4);
    conv4_k<<<192, 256, 0, stream>>>(W_hh, W_hh16, 768 * 256 / 4);
    transpose16_k<<<256, 256, 0, stream>>>(Ws, WsT16, 0, 256, 256);
    transpose16_k<<<128, 256, 0, stream>>>(We2h_W, We2hT16, 0, 128, 256);
    transpose16_k<<<128, 256, 0, stream>>>(cand_W, candW1T16, 0, 128, 256);
    transpose16_k<<<256, 256, 0, stream>>>(cand_W, candW3T16, 256, 256, 256);
    gemm_k<<<dim3(8, 4), 256, 0, stream>>>(relation_emb, Wr,  nullptr, relWr,  NREL, 256, 128, nullptr, ACT_NONE);
    gemm_k<<<dim3(8, 4), 256, 0, stream>>>(relation_emb, Wqr, nullptr, relWqr, NREL, 256, 128, nullptr, ACT_NONE);
    gemm_k<<<dim3(8, 4), 256, 0, stream>>>(relation_emb, cand_W + 128 * 256, nullptr, relCand, NREL, 256, 128, nullptr, ACT_NONE);
    qdot_k<<<64, 256, 0, stream>>>(query_repr, rank_W, qdot);

    // (2) nodeWs16 = bf16(node_hidden @ Ws)
    gemm16s_k<<<dim3((NNODES + 127) / 128, 2), 256, 0, stream>>>(
        node_hidden, nullptr, nullptr, WsT16, nullptr, nodeWs16, NNODES, 256, 256, ACT_NONE);

    // (3) alpha
    alpha_k<<<M / 32, 256, 0, stream>>>(nodeWs16, relWr, relWqr, bqr, w_alpha, b_alpha,
                                        head_node, edge_rel, query_rel, alpha);

    // (4) segment sum via CSR -> bf16 agg
    agg_csr16_k<<<NNEW / 4, 256, 0, stream>>>(relation_emb, entity16, alpha,
                                              edge_rel, tail_ent, offsets, csr, agg16);

    // (5) h_prev16 = bf16(lrelu(entity16[tail_node_ent] @ We2h + b))
    gemm16s_k<<<dim3((NNEW + 127) / 128, 2), 256, 0, stream>>>(
        nullptr, entity16, tail_node_ent, We2hT16, We2h_b, h_prev16, NNEW, 256, 128, ACT_LRELU);

    // (6,7) GRU chunks (gx/gh alias the nodeWs16 region — alpha already done)
    for (int ch = 0; ch < NCHUNK; ++ch) {
        int n0 = ch * NC;
        gemm16s_k<<<dim3((NC + 127) / 128, 6), 256, 0, stream>>>(
            nullptr, agg16 + (size_t)n0 * 256, nullptr, W_ih16, b_ih, gx16, NC, 768, 256, ACT_NONE);
        gemm16s_k<<<dim3((NC + 127) / 128, 6), 256, 0, stream>>>(
            nullptr, h_prev16 + (size_t)n0 * 256, nullptr, W_hh16, b_hh, gh16, NC, 768, 256, ACT_NONE);
        gru_ln16_k<<<NC / 4, 256, 0, stream>>>(gx16, gh16, h_prev16, ln_g, ln_b, h_new16, n0);
    }

    // (8) hnewCand16 = bf16(h_new @ cand_W[256:512] + cand_b)
    gemm16s_k<<<dim3((NNEW + 127) / 128, 2), 256, 0, stream>>>(
        nullptr, h_new16, nullptr, candW3T16, cand_b, hnewCand16, NNEW, 256, 256, ACT_NONE);

    // (9) fused score
    score_mfma3_k<<<M / 64, 256, 0, stream>>>(entity16, candW1T16, relCand, hnewCand16,
                                              rank_W, rank_b, qdot, tail_ent, edge_rel,
                                              tail_node, batch_idx, out);
}